// Round 12
// baseline (208.340 us; speedup 1.0000x reference)
//
#include <hip/hip_runtime.h>

#define VOCAB   32000
#define D       128
#define NNODES  50000
#define NEDGES  600000

typedef unsigned short ushort_t;
typedef unsigned int   uint_t;
typedef __attribute__((ext_vector_type(8))) __bf16 bf16x8;
typedef __attribute__((ext_vector_type(4))) float  f32x4;

__device__ __forceinline__ float bf2f(ushort_t u) {
    union { uint_t i; float f; } c; c.i = ((uint_t)u) << 16; return c.f;
}
__device__ __forceinline__ ushort_t f2bf(float f) {
    union { float f; uint_t i; } c; c.f = f;
    uint_t u = c.i;
    u += 0x7fff + ((u >> 16) & 1);            // round-to-nearest-even
    return (ushort_t)(u >> 16);
}

union PkAB { uint_t u[4]; bf16x8 v; };

// ---------------------------------------------------------------------------
// MFMA table MLP + fused dst-histogram (proven: round 8, 207 us, absmax 0.5).
// GEMM: [32000 x 128] emb  x  [128 x 256] (w1|w2)  + (b1|b2), relu, bf16 out.
// Block = 4 waves; wave wv owns 64 cols: wv 0,1 -> t1, wv 2,3 -> t2.
// B (w) fragments live in VGPRs (loaded once, bf16); no LDS at all.
// ---------------------------------------------------------------------------
__global__ __launch_bounds__(256) void mlp_mfma_hist_kernel(
    const float* __restrict__ emb,
    const float* __restrict__ w1, const float* __restrict__ b1,
    const float* __restrict__ w2, const float* __restrict__ b2,
    ushort_t* __restrict__ t1, ushort_t* __restrict__ t2,
    const int* __restrict__ dstv, int* __restrict__ counts)
{
    // histogram slice: 600 edges/block, hidden under the GEMM
    {
        const int base = blockIdx.x * (NEDGES / 1000);
        for (int i = base + threadIdx.x; i < base + NEDGES / 1000; i += 256)
            atomicAdd(&counts[dstv[i]], 1);
    }

    const int wv   = threadIdx.x >> 6;     // wave 0..3
    const int lane = threadIdx.x & 63;
    const int jcol = lane & 15;
    const int krow = (lane >> 4) * 8;      // 0,8,16,24

    const float* __restrict__ wsel = (wv >= 2) ? w2 : w1;
    const float* __restrict__ bsel = (wv >= 2) ? b2 : b1;
    ushort_t*    __restrict__ osel = (wv >= 2) ? t2 : t1;
    const int colT = (wv & 1) * 64;        // col base inside the table

    // B fragments [n][kk]: B[k = kk*32 + krow + e][col = colT + n*16 + jcol]
    PkAB bfrag[4][4];
    #pragma unroll
    for (int n = 0; n < 4; ++n) {
        const int c = colT + n * 16 + jcol;
        #pragma unroll
        for (int kk = 0; kk < 4; ++kk) {
            const int k0 = kk * 32 + krow;
            #pragma unroll
            for (int e = 0; e < 4; ++e) {
                const float lo = wsel[(size_t)(k0 + 2 * e)     * D + c];
                const float hi = wsel[(size_t)(k0 + 2 * e + 1) * D + c];
                bfrag[n][kk].u[e] = (uint_t)f2bf(lo) | ((uint_t)f2bf(hi) << 16);
            }
        }
    }

    float bval[4];
    #pragma unroll
    for (int n = 0; n < 4; ++n) bval[n] = bsel[colT + n * 16 + jcol];

    #pragma unroll
    for (int it = 0; it < 2; ++it) {
        const int rowbase = (it * 1000 + blockIdx.x) * 16;
        const float* __restrict__ aptr =
            emb + (size_t)(rowbase + jcol) * D + krow;

        // A fragments: A[row = rowbase + jcol][k = kk*32 + krow + e]
        PkAB afrag[4];
        #pragma unroll
        for (int kk = 0; kk < 4; ++kk) {
            const float4 xa = *(const float4*)(aptr + kk * 32);
            const float4 xb = *(const float4*)(aptr + kk * 32 + 4);
            afrag[kk].u[0] = (uint_t)f2bf(xa.x) | ((uint_t)f2bf(xa.y) << 16);
            afrag[kk].u[1] = (uint_t)f2bf(xa.z) | ((uint_t)f2bf(xa.w) << 16);
            afrag[kk].u[2] = (uint_t)f2bf(xb.x) | ((uint_t)f2bf(xb.y) << 16);
            afrag[kk].u[3] = (uint_t)f2bf(xb.z) | ((uint_t)f2bf(xb.w) << 16);
        }

        f32x4 acc[4];
        #pragma unroll
        for (int n = 0; n < 4; ++n)
            acc[n] = (f32x4){bval[n], bval[n], bval[n], bval[n]};

        #pragma unroll
        for (int kk = 0; kk < 4; ++kk) {
            #pragma unroll
            for (int n = 0; n < 4; ++n)
                acc[n] = __builtin_amdgcn_mfma_f32_16x16x32_bf16(
                    afrag[kk].v, bfrag[n][kk].v, acc[n], 0, 0, 0);
        }

        #pragma unroll
        for (int n = 0; n < 4; ++n) {
            #pragma unroll
            for (int j = 0; j < 4; ++j) {
                const int row = rowbase + (lane >> 4) * 4 + j;
                osel[(size_t)row * D + colT + n * 16 + jcol] =
                    f2bf(fmaxf(acc[n][j], 0.f));
            }
        }
    }
}

// ---------------------------------------------------------------------------
// Hierarchical scan (phase1: per-block excl scan + totals; phase2: add prefix)
// ---------------------------------------------------------------------------
__global__ __launch_bounds__(256) void scan_phase1(
    const int* __restrict__ counts,
    int* __restrict__ offs,
    int* __restrict__ btot)
{
    const int i    = blockIdx.x * 256 + threadIdx.x;
    const int lane = threadIdx.x & 63;
    const int wv   = threadIdx.x >> 6;

    const int v = (i < NNODES) ? counts[i] : 0;
    int inc = v;
    #pragma unroll
    for (int off = 1; off < 64; off <<= 1) {
        int u = __shfl_up(inc, off);
        if (lane >= off) inc += u;
    }
    __shared__ int wtot[4];
    if (lane == 63) wtot[wv] = inc;
    __syncthreads();
    int wpre = 0;
    #pragma unroll
    for (int k = 0; k < 3; ++k) if (k < wv) wpre += wtot[k];
    inc += wpre;
    if (i < NNODES) offs[i] = inc - v;
    if (threadIdx.x == 255) btot[blockIdx.x] = inc;
}

__global__ __launch_bounds__(256) void scan_phase2(
    const int* __restrict__ btot,
    int* __restrict__ offs,
    int* __restrict__ cursor,
    int nblocks)
{
    const int t    = threadIdx.x;
    const int lane = t & 63;
    const int wv   = t >> 6;

    int v = (t < blockIdx.x && t < nblocks) ? btot[t] : 0;
    #pragma unroll
    for (int off = 32; off > 0; off >>= 1) v += __shfl_xor(v, off);
    __shared__ int ws[4];
    if (lane == 0) ws[wv] = v;
    __syncthreads();
    const int bpre = ws[0] + ws[1] + ws[2] + ws[3];

    const int i = blockIdx.x * 256 + t;
    if (i < NNODES) {
        const int o = offs[i] + bpre;
        offs[i]   = o;
        cursor[i] = o;
    }
    if (blockIdx.x == 0 && t == 0) offs[NNODES] = NEDGES;
}

// ---------------------------------------------------------------------------
// Scatter packed (tn | te<<16) pairs into CSR buckets
// ---------------------------------------------------------------------------
__global__ __launch_bounds__(256) void scatter_kernel(
    const int4* __restrict__ src4, const int4* __restrict__ dst4,
    const int* __restrict__ node_tokens, const int4* __restrict__ et4,
    int* __restrict__ cursor, uint_t* __restrict__ pairs)
{
    const int t = blockIdx.x * 256 + threadIdx.x;
    if (t >= NEDGES / 4) return;
    const int4 s = src4[t];
    const int4 d = dst4[t];
    const int4 te = et4[t];
    int p;
    p = atomicAdd(&cursor[d.x], 1);
    pairs[p] = (uint_t)node_tokens[s.x] | ((uint_t)te.x << 16);
    p = atomicAdd(&cursor[d.y], 1);
    pairs[p] = (uint_t)node_tokens[s.y] | ((uint_t)te.y << 16);
    p = atomicAdd(&cursor[d.z], 1);
    pairs[p] = (uint_t)node_tokens[s.z] | ((uint_t)te.z << 16);
    p = atomicAdd(&cursor[d.w], 1);
    pairs[p] = (uint_t)node_tokens[s.w] | ((uint_t)te.w << 16);
}

// ---------------------------------------------------------------------------
// Gather: one wave per node; half-wave edge split (PROVEN round-8 structure —
// do not modify without disasm evidence; two ILP variants failed correctness).
// bf16 table rows (256 B): sublane sl loads ushort4 -> 4 output columns.
// f32 accumulate, shfl_xor(32) combine, one coalesced float4 row write.
// ---------------------------------------------------------------------------
__global__ __launch_bounds__(256) void gather_kernel(
    const ushort_t* __restrict__ t1, const ushort_t* __restrict__ t2,
    const int* __restrict__ offsets, const uint_t* __restrict__ pairs,
    float* __restrict__ outp)
{
    const int wid = (blockIdx.x * 256 + threadIdx.x) >> 6;
    if (wid >= NNODES) return;
    const int lane = threadIdx.x & 63;
    const int half = lane >> 5;
    const int sl   = lane & 31;

    const int beg = offsets[wid];
    const int end = offsets[wid + 1];

    float4 acc = {0.f, 0.f, 0.f, 0.f};
    for (int base = beg; base < end; base += 64) {
        const int m = min(64, end - base);
        uint_t pr = (lane < m) ? pairs[base + lane] : 0u;
        for (int j = half; j < m; j += 2) {
            const uint_t v = (uint_t)__shfl((int)pr, j);
            const int tn = (int)(v & 0xffffu);
            const int te = (int)(v >> 16);
            const ushort4 a  = ((const ushort4*)(t1 + (size_t)tn * D))[sl];
            const ushort4 bb = ((const ushort4*)(t2 + (size_t)te * D))[sl];
            acc.x = fmaf(bf2f(a.x), bf2f(bb.x), acc.x);
            acc.y = fmaf(bf2f(a.y), bf2f(bb.y), acc.y);
            acc.z = fmaf(bf2f(a.z), bf2f(bb.z), acc.z);
            acc.w = fmaf(bf2f(a.w), bf2f(bb.w), acc.w);
        }
    }
    acc.x += __shfl_xor(acc.x, 32);
    acc.y += __shfl_xor(acc.y, 32);
    acc.z += __shfl_xor(acc.z, 32);
    acc.w += __shfl_xor(acc.w, 32);
    if (half == 0)
        ((float4*)(outp + (size_t)wid * D))[sl] = acc;
}

extern "C" void kernel_launch(void* const* d_in, const int* in_sizes, int n_in,
                              void* d_out, int out_size, void* d_ws, size_t ws_size,
                              hipStream_t stream) {
    const float* emb = (const float*)d_in[0];
    const float* w1  = (const float*)d_in[1];
    const float* b1  = (const float*)d_in[2];
    const float* w2  = (const float*)d_in[3];
    const float* b2  = (const float*)d_in[4];
    const int* node_tokens = (const int*)d_in[5];
    const int* edge_tokens = (const int*)d_in[6];
    const int* src = (const int*)d_in[7];
    const int* dst = (const int*)d_in[8];
    float* out = (float*)d_out;

    // workspace layout (bytes)
    char* wsb = (char*)d_ws;
    ushort_t* t1     = (ushort_t*)(wsb);               //  8,192,000
    ushort_t* t2     = (ushort_t*)(wsb +  8192000);    //  8,192,000
    uint_t*   pairs  = (uint_t*)  (wsb + 16384000);    //  2,400,000
    int*      counts = (int*)     (wsb + 18784000);    //    200,000
    int*      offs   = (int*)     (wsb + 18984000);    //    200,004
    int*      cursor = (int*)     (wsb + 19184016);    //    200,000
    int*      btot   = (int*)     (wsb + 19384016);    //        784

    hipMemsetAsync(counts, 0, NNODES * sizeof(int), stream);

    // fused histogram + both table MLPs via MFMA
    mlp_mfma_hist_kernel<<<1000, 256, 0, stream>>>(emb, w1, b1, w2, b2,
                                                   t1, t2, dst, counts);

    const int nscan = (NNODES + 255) / 256;            // 196
    scan_phase1<<<nscan, 256, 0, stream>>>(counts, offs, btot);
    scan_phase2<<<nscan, 256, 0, stream>>>(btot, offs, cursor, nscan);
    scatter_kernel<<<(NEDGES / 4 + 255) / 256, 256, 0, stream>>>(
        (const int4*)src, (const int4*)dst, node_tokens,
        (const int4*)edge_tokens, cursor, pairs);

    gather_kernel<<<(NNODES + 3) / 4, 256, 0, stream>>>(t1, t2, offs, pairs, out);
}